// Round 10
// baseline (121.613 us; speedup 1.0000x reference)
//
#include <hip/hip_runtime.h>

// Depthwise 3x3 conv, NHWC, stride 1, SAME, fp32.
// x: (32,112,112,192), w: (3,3,1,192), b: (192), out: (32,112,112,192)
//
// R10: pure-register rolling pipeline (no LDS, no barriers). Each thread
//      computes 2 w-adjacent x 8 h-adjacent float4 outputs from a rolling
//      5-row x 4-col register window (prefetch depth 2 rows, ring-5,
//      fully unrolled -> all-static indexing). Issued reads 2.5 f4/output
//      (R4's batch path sustained ~18 TB/s issued; LDS pipelines plateaued
//      at 107-117 us regardless of occupancy/depth -> structural).
//      Branchless SAME padding: clamped addresses + validity multiplies.

constexpr int Bn = 32, Hn = 112, Wn = 112, Cn = 192, C4 = 48;
constexpr int HT = 8, HTiles = 14;   // output rows per thread
constexpr int W2n = 56;              // w-pair index range (2 outputs wide)

typedef float floatx4 __attribute__((ext_vector_type(4)));

__device__ __forceinline__ floatx4 fma4(floatx4 a, floatx4 b, floatx4 c) {
  c.x = fmaf(a.x, b.x, c.x);
  c.y = fmaf(a.y, b.y, c.y);
  c.z = fmaf(a.z, b.z, c.z);
  c.w = fmaf(a.w, b.w, c.w);
  return c;
}

__global__ __launch_bounds__(256, 3) void dwconv3x3_reg(
    const float* __restrict__ x,
    const float* __restrict__ wgt,   // (3,3,1,192)
    const float* __restrict__ bias,  // (192)
    float* __restrict__ out) {
  // Chunked XCD swizzle (4704 % 8 == 0): h-neighbor thread groups share L2.
  int bid = blockIdx.x;
  int chk = gridDim.x >> 3;  // 588
  int sbid = (bid & 7) * chk + (bid >> 3);
  int i = sbid * 256 + (int)threadIdx.x;

  // i -> (b, ht, w2, c4), c4 innermost (lane-contiguous 16B loads/stores).
  int c4 = i % C4; int t = i / C4;
  int w2 = t % W2n; t /= W2n;
  int ht = t % HTiles; int b = t / HTiles;
  int c = c4 * 4, w0 = w2 * 2, h0 = ht * HT;

  const int rstr = Wn * Cn;
  const float* xb = x + (long)b * Hn * rstr + c;

  // 4 input cols: w0-1, w0, w0+1, w0+2 (clamped; validity via multiplies).
  int co[4];
  co[0] = max(w0 - 1, 0) * Cn;
  co[1] = w0 * Cn;
  co[2] = (w0 + 1) * Cn;
  co[3] = min(w0 + 2, Wn - 1) * Cn;
  const float csA = (w0 >= 1) ? 1.f : 0.f;
  const float csB = (w0 + 2 <= Wn - 1) ? 1.f : 0.f;
  const float sTop = (ht == 0) ? 0.f : 1.f;
  const float sBot = (ht == HTiles - 1) ? 0.f : 1.f;

  // Weights + bias (6.9 KB table, L1-resident).
  floatx4 wv[3][3];
#pragma unroll
  for (int kh = 0; kh < 3; ++kh)
#pragma unroll
    for (int kw = 0; kw < 3; ++kw)
      wv[kh][kw] = *(const floatx4*)(wgt + (kh * 3 + kw) * Cn + c);
  const floatx4 bv = *(const floatx4*)(bias + c);

  // Rolling window: staged row r (0..9) = input h = h0+r-1; slot = r % 5.
  floatx4 xv[5][4];

  // Prologue: rows 0..3 (row 0 top-clamped + sTop-scaled).
  {
    int h = max(h0 - 1, 0);
    const float* rp = xb + (long)h * rstr;
    xv[0][0] = *(const floatx4*)(rp + co[0]);
    xv[0][1] = *(const floatx4*)(rp + co[1]);
    xv[0][2] = *(const floatx4*)(rp + co[2]);
    xv[0][3] = *(const floatx4*)(rp + co[3]);
  }
#pragma unroll
  for (int r = 1; r <= 3; ++r) {
    const float* rp = xb + (long)(h0 + r - 1) * rstr;
    xv[r][0] = *(const floatx4*)(rp + co[0]);
    xv[r][1] = *(const floatx4*)(rp + co[1]);
    xv[r][2] = *(const floatx4*)(rp + co[2]);
    xv[r][3] = *(const floatx4*)(rp + co[3]);
  }
  // Validity scales (after issue, so loads overlap the VALU).
  xv[0][0] *= sTop * csA; xv[0][1] *= sTop; xv[0][2] *= sTop; xv[0][3] *= sTop * csB;
#pragma unroll
  for (int r = 1; r <= 3; ++r) { xv[r][0] *= csA; xv[r][3] *= csB; }

  const int ostr = Wn * C4;  // 5376 f4 per output row
  floatx4* op = (floatx4*)out + ((long)(b * Hn + h0) * Wn + w0) * C4 + c4;

#pragma unroll
  for (int o = 0; o < HT; ++o) {
    // Prefetch row o+4 (used first at step o+2 -> depth-2 latency slack).
    const int rn = o + 4;
    if (rn <= 9) {
      const int s = rn % 5;
      int h = (rn == 9) ? min(h0 + 8, Hn - 1) : (h0 + rn - 1);
      const float* rp = xb + (long)h * rstr;
      xv[s][0] = *(const floatx4*)(rp + co[0]);
      xv[s][1] = *(const floatx4*)(rp + co[1]);
      xv[s][2] = *(const floatx4*)(rp + co[2]);
      xv[s][3] = *(const floatx4*)(rp + co[3]);
      xv[s][0] *= csA; xv[s][3] *= csB;
      if (rn == 9) {
        xv[s][0] *= sBot; xv[s][1] *= sBot; xv[s][2] *= sBot; xv[s][3] *= sBot;
      }
    }

    // Output rows h0+o (cols w0, w0+1) from staged rows o, o+1, o+2.
    floatx4 a0 = bv, a1 = bv;
#pragma unroll
    for (int kh = 0; kh < 3; ++kh) {
      const int s = (o + kh) % 5;  // compile-time after unroll
      a0 = fma4(xv[s][0], wv[kh][0], a0);
      a0 = fma4(xv[s][1], wv[kh][1], a0);
      a0 = fma4(xv[s][2], wv[kh][2], a0);
      a1 = fma4(xv[s][1], wv[kh][0], a1);
      a1 = fma4(xv[s][2], wv[kh][1], a1);
      a1 = fma4(xv[s][3], wv[kh][2], a1);
    }
    __builtin_nontemporal_store(a0, op);
    __builtin_nontemporal_store(a1, op + C4);
    op += ostr;
  }
}

extern "C" void kernel_launch(void* const* d_in, const int* in_sizes, int n_in,
                              void* d_out, int out_size, void* d_ws, size_t ws_size,
                              hipStream_t stream) {
  const float* x = (const float*)d_in[0];
  const float* w = (const float*)d_in[1];
  const float* b = (const float*)d_in[2];
  float* out = (float*)d_out;

  // 1,204,224 threads (16 f4 outputs each) = 4704 blocks (divisible by 8).
  const int grid = Bn * HTiles * W2n * C4 / 256;
  dwconv3x3_reg<<<grid, 256, 0, stream>>>(x, w, b, out);
}